// Round 12
// baseline (292.368 us; speedup 1.0000x reference)
//
#include <hip/hip_runtime.h>

// EquivariantCombination (iro=1, fro=1) on MI355X.
// Inputs:  tensor [B=256][F=64][3] fp32, f [A=1024][B=256][F=64][3] fp32
// Outputs: o0 [A][F][1] then o1 [A][F][3], concatenated flat in d_out (fp32).
//
// o0[a,fc]   = sum_b (sum_j f[a,b,fc,j]) * (sum_k tensor[b,fc,k])
// o1[a,fc,:] = sum_b cross(f[a,b,fc,:], tensor[b,fc,:])
//
// Memory-bound: f = 201 MB streamed once -> ~32 us floor @ 6.3 TB/s.
// R9 measured kernel ~41 us (~4.9 TB/s). This round: occupancy 16->32
// waves/CU. 1024 blocks x 512 thr (4 blocks/CU x 8 waves = 100%).
// __launch_bounds__(512,8) caps VGPR at 64 (unroll 1 keeps ~48 live).
// Thread t: fcg = t&15 (4 consecutive channels = 3 aligned float4),
// bslot = t>>4 (0..31); b = bslot + 32k, k=0..7. Nontemporal f loads.
// LDS reduce (stride-5 padded) epilogue: 40 KB x 4 blocks = 160 KB.

#define A_DIM 1024
#define B_DIM 256
#define F_DIM 64

typedef float f32x4 __attribute__((ext_vector_type(4)));

__global__ __launch_bounds__(512, 8) void equiv_comb_kernel(
    const float* __restrict__ tensor,   // [B][F][3]
    const float* __restrict__ f,        // [A][B][F][3]
    float* __restrict__ out)            // [A*F] o0, then [A*F*3] o1
{
    const int a     = blockIdx.x;
    const int t     = threadIdx.x;
    const int fcg   = t & 15;           // feature-channel group of 4
    const int bslot = t >> 4;           // 0..31

    const float* __restrict__ fbase = f + (size_t)a * (B_DIM * F_DIM * 3);

    float a0[4] = {0.f, 0.f, 0.f, 0.f};
    float cx[4] = {0.f, 0.f, 0.f, 0.f};
    float cy[4] = {0.f, 0.f, 0.f, 0.f};
    float cz[4] = {0.f, 0.f, 0.f, 0.f};

    #pragma unroll 1
    for (int k = 0; k < 8; ++k) {
        const int b = bslot + (k << 5);
        const f32x4* __restrict__ fp =
            reinterpret_cast<const f32x4*>(fbase  + (size_t)b * (F_DIM * 3) + fcg * 12);
        const f32x4* __restrict__ tp =
            reinterpret_cast<const f32x4*>(tensor + (size_t)b * (F_DIM * 3) + fcg * 12);

        const f32x4 fl0 = __builtin_nontemporal_load(fp + 0);
        const f32x4 fl1 = __builtin_nontemporal_load(fp + 1);
        const f32x4 fl2 = __builtin_nontemporal_load(fp + 2);
        const f32x4 tl0 = tp[0];
        const f32x4 tl1 = tp[1];
        const f32x4 tl2 = tp[2];

        const float fv[12] = {fl0.x, fl0.y, fl0.z, fl0.w,
                              fl1.x, fl1.y, fl1.z, fl1.w,
                              fl2.x, fl2.y, fl2.z, fl2.w};
        const float tv[12] = {tl0.x, tl0.y, tl0.z, tl0.w,
                              tl1.x, tl1.y, tl1.z, tl1.w,
                              tl2.x, tl2.y, tl2.z, tl2.w};

        #pragma unroll
        for (int q = 0; q < 4; ++q) {
            const float f0 = fv[q * 3 + 0], f1 = fv[q * 3 + 1], f2 = fv[q * 3 + 2];
            const float t0 = tv[q * 3 + 0], t1 = tv[q * 3 + 1], t2 = tv[q * 3 + 2];
            a0[q] += (f0 + f1 + f2) * (t0 + t1 + t2);
            cx[q] += f1 * t2 - f2 * t1;
            cy[q] += f2 * t0 - f0 * t2;
            cz[q] += f0 * t1 - f1 * t0;
        }
    }

    // Cross-bslot reduction through LDS. Stride 5 -> conflict-light.
    __shared__ float red[32][F_DIM][5];
    #pragma unroll
    for (int q = 0; q < 4; ++q) {
        const int fc = fcg * 4 + q;
        red[bslot][fc][0] = a0[q];
        red[bslot][fc][1] = cx[q];
        red[bslot][fc][2] = cy[q];
        red[bslot][fc][3] = cz[q];
    }
    __syncthreads();

    if (t < F_DIM) {
        float s0 = 0.f, s1 = 0.f, s2 = 0.f, s3 = 0.f;
        #pragma unroll
        for (int s = 0; s < 32; ++s) {
            s0 += red[s][t][0];
            s1 += red[s][t][1];
            s2 += red[s][t][2];
            s3 += red[s][t][3];
        }
        out[a * F_DIM + t] = s0;                                   // o0
        float* __restrict__ o1 = out + A_DIM * F_DIM + (size_t)(a * F_DIM + t) * 3;
        o1[0] = s1;
        o1[1] = s2;
        o1[2] = s3;
    }
}

extern "C" void kernel_launch(void* const* d_in, const int* in_sizes, int n_in,
                              void* d_out, int out_size, void* d_ws, size_t ws_size,
                              hipStream_t stream) {
    const float* tensor = (const float*)d_in[0];   // [B,F,3]
    const float* f      = (const float*)d_in[1];   // [A,B,F,3]
    float* out          = (float*)d_out;           // 65536 + 196608 floats

    equiv_comb_kernel<<<dim3(A_DIM), dim3(512), 0, stream>>>(tensor, f, out);
}

// Round 14
// 282.897 us; speedup vs baseline: 1.0335x; 1.0335x over previous
//
#include <hip/hip_runtime.h>

// EquivariantCombination (iro=1, fro=1) on MI355X.
// Inputs:  tensor [B=256][F=64][3] fp32, f [A=1024][B=256][F=64][3] fp32
// Outputs: o0 [A][F][1] then o1 [A][F][3], concatenated flat in d_out (fp32).
//
// o0[a,fc]   = sum_b (sum_j f[a,b,fc,j]) * (sum_k tensor[b,fc,k])
// o1[a,fc,:] = sum_b cross(f[a,b,fc,:], tensor[b,fc,:])
//
// Memory-bound: f = 201 MB streamed once -> ~32 us floor @ 6.3 TB/s.
// History: scalar ~49us; R9 (256thr, unroll2, float4+NT) ~41us = 4.9 TB/s;
// R12 (512thr, unroll1) REGRESSED to ~55us -> limiter is per-thread ILP
// (outstanding loads), not wave count. This round: R9 structure + unroll 4
// (12 NT f-loads in flight/thread; compute-cover/SIMD ~1600cy > 900cy HBM
// latency). VGPR est ~85 < 128 cap for 4 waves/SIMD.
//
// Thread t: fcg = t&15 (4 consecutive channels = 3 aligned float4),
// bslot = t>>4 (0..15); b = bslot + 16k, k=0..15. LDS reduce epilogue.

#define A_DIM 1024
#define B_DIM 256
#define F_DIM 64

typedef float f32x4 __attribute__((ext_vector_type(4)));

__global__ __launch_bounds__(256, 4) void equiv_comb_kernel(
    const float* __restrict__ tensor,   // [B][F][3]
    const float* __restrict__ f,        // [A][B][F][3]
    float* __restrict__ out)            // [A*F] o0, then [A*F*3] o1
{
    const int a     = blockIdx.x;
    const int t     = threadIdx.x;
    const int fcg   = t & 15;           // feature-channel group of 4
    const int bslot = t >> 4;           // 0..15

    const float* __restrict__ fbase = f + (size_t)a * (B_DIM * F_DIM * 3);

    float a0[4] = {0.f, 0.f, 0.f, 0.f};
    float cx[4] = {0.f, 0.f, 0.f, 0.f};
    float cy[4] = {0.f, 0.f, 0.f, 0.f};
    float cz[4] = {0.f, 0.f, 0.f, 0.f};

    #pragma unroll 4
    for (int k = 0; k < 16; ++k) {
        const int b = bslot + (k << 4);
        const f32x4* __restrict__ fp =
            reinterpret_cast<const f32x4*>(fbase  + (size_t)b * (F_DIM * 3) + fcg * 12);
        const f32x4* __restrict__ tp =
            reinterpret_cast<const f32x4*>(tensor + (size_t)b * (F_DIM * 3) + fcg * 12);

        const f32x4 fl0 = __builtin_nontemporal_load(fp + 0);
        const f32x4 fl1 = __builtin_nontemporal_load(fp + 1);
        const f32x4 fl2 = __builtin_nontemporal_load(fp + 2);
        const f32x4 tl0 = tp[0];
        const f32x4 tl1 = tp[1];
        const f32x4 tl2 = tp[2];

        const float fv[12] = {fl0.x, fl0.y, fl0.z, fl0.w,
                              fl1.x, fl1.y, fl1.z, fl1.w,
                              fl2.x, fl2.y, fl2.z, fl2.w};
        const float tv[12] = {tl0.x, tl0.y, tl0.z, tl0.w,
                              tl1.x, tl1.y, tl1.z, tl1.w,
                              tl2.x, tl2.y, tl2.z, tl2.w};

        #pragma unroll
        for (int q = 0; q < 4; ++q) {
            const float f0 = fv[q * 3 + 0], f1 = fv[q * 3 + 1], f2 = fv[q * 3 + 2];
            const float t0 = tv[q * 3 + 0], t1 = tv[q * 3 + 1], t2 = tv[q * 3 + 2];
            a0[q] += (f0 + f1 + f2) * (t0 + t1 + t2);
            cx[q] += f1 * t2 - f2 * t1;
            cy[q] += f2 * t0 - f0 * t2;
            cz[q] += f0 * t1 - f1 * t0;
        }
    }

    // Cross-bslot reduction through LDS. Stride 5 -> bank-conflict-free.
    __shared__ float red[16][F_DIM][5];
    #pragma unroll
    for (int q = 0; q < 4; ++q) {
        const int fc = fcg * 4 + q;
        red[bslot][fc][0] = a0[q];
        red[bslot][fc][1] = cx[q];
        red[bslot][fc][2] = cy[q];
        red[bslot][fc][3] = cz[q];
    }
    __syncthreads();

    if (t < F_DIM) {
        float s0 = 0.f, s1 = 0.f, s2 = 0.f, s3 = 0.f;
        #pragma unroll
        for (int s = 0; s < 16; ++s) {
            s0 += red[s][t][0];
            s1 += red[s][t][1];
            s2 += red[s][t][2];
            s3 += red[s][t][3];
        }
        out[a * F_DIM + t] = s0;                                   // o0
        float* __restrict__ o1 = out + A_DIM * F_DIM + (size_t)(a * F_DIM + t) * 3;
        o1[0] = s1;
        o1[1] = s2;
        o1[2] = s3;
    }
}

extern "C" void kernel_launch(void* const* d_in, const int* in_sizes, int n_in,
                              void* d_out, int out_size, void* d_ws, size_t ws_size,
                              hipStream_t stream) {
    const float* tensor = (const float*)d_in[0];   // [B,F,3]
    const float* f      = (const float*)d_in[1];   // [A,B,F,3]
    float* out          = (float*)d_out;           // 65536 + 196608 floats

    equiv_comb_kernel<<<dim3(A_DIM), dim3(256), 0, stream>>>(tensor, f, out);
}